// Round 1
// baseline (3618.634 us; speedup 1.0000x reference)
//
#include <hip/hip_runtime.h>
#include <math.h>

#define NTH 256

__device__ __forceinline__ unsigned enc_f(float x){
  unsigned u = __float_as_uint(x);
  return (u & 0x80000000u) ? ~u : (u | 0x80000000u);
}
__device__ __forceinline__ float dec_f(unsigned v){
  unsigned u = (v & 0x80000000u) ? (v & 0x7FFFFFFFu) : ~v;
  return __uint_as_float(u);
}

// ---------------------------------------------------------------------------
// Node linear: out[N,DO] = x[N,DI] @ W[DI,DO] (+ bias)
// Register tile: each thread computes 2 rows x 4 cols. TR=64 rows/chunk,
// DO tiled by 32. DIP pads LDS stride (+4) so row-pair strides hit different
// banks (2-way max, free per m136).
// ---------------------------------------------------------------------------
template<int DI, int DO>
__global__ __launch_bounds__(NTH) void node_linear_k(
    const float* __restrict__ x, const float* __restrict__ W,
    const float* __restrict__ bias, float* __restrict__ out, int N)
{
  constexpr int TR = 64;
  constexpr int DOTP = 32;
  constexpr int DIP = ((DI + 3) & ~3) + 4;
  __shared__ float sX[TR * DIP];
  __shared__ float sW[DIP * DOTP];
  const int tid = threadIdx.x;
  const int lg = tid >> 3;   // 0..31 -> row pair
  const int cg = tid & 7;    // 0..7  -> col quad
  const int nchunks = (N + TR - 1) / TR;
  for (int c = blockIdx.x; c < nchunks; c += gridDim.x) {
    const int r0 = c * TR;
    __syncthreads();
    for (int i = tid; i < TR * DIP; i += NTH) {
      int le = i / DIP, k = i - le * DIP;
      int r = r0 + le;
      sX[i] = (k < DI && r < N) ? x[(size_t)r * DI + k] : 0.f;
    }
    __syncthreads();
    for (int ct = 0; ct < DO; ct += DOTP) {
      if (ct) __syncthreads();
      for (int i = tid; i < DIP * DOTP; i += NTH) {
        int k = i >> 5, j = i & 31;
        int col = ct + j;
        sW[i] = (k < DI && col < DO) ? W[k * DO + col] : 0.f;
      }
      __syncthreads();
      float acc[2][4];
      #pragma unroll
      for (int li = 0; li < 2; li++)
        #pragma unroll
        for (int cc = 0; cc < 4; cc++) {
          int col = ct + cg * 4 + cc;
          acc[li][cc] = (bias != nullptr && col < DO) ? bias[col] : 0.f;
        }
      const int b0 = (lg * 2 + 0) * DIP;
      const int b1 = (lg * 2 + 1) * DIP;
      for (int k = 0; k < DIP; k += 4) {
        float4 e0 = *(const float4*)&sX[b0 + k];
        float4 e1 = *(const float4*)&sX[b1 + k];
        float ea0[4] = {e0.x, e0.y, e0.z, e0.w};
        float ea1[4] = {e1.x, e1.y, e1.z, e1.w};
        #pragma unroll
        for (int kk = 0; kk < 4; kk++) {
          float4 wv = *(const float4*)&sW[(k + kk) * DOTP + cg * 4];
          acc[0][0] += ea0[kk] * wv.x; acc[0][1] += ea0[kk] * wv.y;
          acc[0][2] += ea0[kk] * wv.z; acc[0][3] += ea0[kk] * wv.w;
          acc[1][0] += ea1[kk] * wv.x; acc[1][1] += ea1[kk] * wv.y;
          acc[1][2] += ea1[kk] * wv.z; acc[1][3] += ea1[kk] * wv.w;
        }
      }
      #pragma unroll
      for (int li = 0; li < 2; li++) {
        int r = r0 + lg * 2 + li;
        if (r < N) {
          if constexpr (DO % 4 == 0) {
            float4 st = make_float4(acc[li][0], acc[li][1], acc[li][2], acc[li][3]);
            *(float4*)&out[(size_t)r * DO + ct + cg * 4] = st;
          } else {
            #pragma unroll
            for (int cc = 0; cc < 4; cc++) {
              int col = ct + cg * 4 + cc;
              if (col < DO) out[(size_t)r * DO + col] = acc[li][cc];
            }
          }
        }
      }
    }
  }
}

// ---------------------------------------------------------------------------
// Edge kernel: f = leaky_relu(xWni[src] + xWnj[dst] + e@Wf + bias)
// Optionally computes score = sum(f*attn) per edge and atomicMax into menc.
// Same 2x4 register tile; score reduced via shfl over the 8-lane col groups.
// ---------------------------------------------------------------------------
template<int DI, int DO, bool SCORE>
__global__ __launch_bounds__(NTH) void edge_f_k(
    const float* __restrict__ efeat, const float* __restrict__ xWni,
    const float* __restrict__ xWnj, const float* __restrict__ Wf,
    const float* __restrict__ attn, const float* __restrict__ bias,
    const int* __restrict__ src, const int* __restrict__ dst,
    float* __restrict__ fout, float* __restrict__ score,
    unsigned* __restrict__ menc, int E)
{
  constexpr int TE = 64;
  constexpr int DOTP = 32;
  constexpr int DIP = ((DI + 3) & ~3) + 4;
  __shared__ float sE[TE * DIP];
  __shared__ float sW[DIP * DOTP];
  __shared__ float sScore[TE];
  __shared__ int sSrc[TE];
  __shared__ int sDst[TE];
  const int tid = threadIdx.x;
  const int lg = tid >> 3;
  const int cg = tid & 7;
  const int nchunks = (E + TE - 1) / TE;
  for (int c = blockIdx.x; c < nchunks; c += gridDim.x) {
    const int e0 = c * TE;
    const int ne = min(TE, E - e0);
    __syncthreads();
    for (int i = tid; i < TE * DIP; i += NTH) {
      int le = i / DIP, k = i - le * DIP;
      sE[i] = (k < DI && le < ne) ? efeat[(size_t)(e0 + le) * DI + k] : 0.f;
    }
    if (tid < TE) {
      int ge = e0 + min(tid, ne - 1);
      sSrc[tid] = src[ge]; sDst[tid] = dst[ge]; sScore[tid] = 0.f;
    }
    __syncthreads();
    for (int ct = 0; ct < DO; ct += DOTP) {
      if (ct) __syncthreads();
      for (int i = tid; i < DIP * DOTP; i += NTH) {
        int k = i >> 5, j = i & 31;
        int col = ct + j;
        sW[i] = (k < DI && col < DO) ? Wf[k * DO + col] : 0.f;
      }
      __syncthreads();
      float acc[2][4];
      #pragma unroll
      for (int li = 0; li < 2; li++) {
        int le = lg * 2 + li;
        int sn = sSrc[le], dn = sDst[le];
        if constexpr (DO % 4 == 0) {
          const float4 a4 = *(const float4*)&xWni[(size_t)sn * DO + ct + cg * 4];
          const float4 b4 = *(const float4*)&xWnj[(size_t)dn * DO + ct + cg * 4];
          const float4 bb = *(const float4*)&bias[ct + cg * 4];
          acc[li][0] = bb.x + a4.x + b4.x;
          acc[li][1] = bb.y + a4.y + b4.y;
          acc[li][2] = bb.z + a4.z + b4.z;
          acc[li][3] = bb.w + a4.w + b4.w;
        } else {
          #pragma unroll
          for (int cc = 0; cc < 4; cc++) {
            int col = ct + cg * 4 + cc;
            acc[li][cc] = (col < DO)
              ? bias[col] + xWni[(size_t)sn * DO + col] + xWnj[(size_t)dn * DO + col]
              : 0.f;
          }
        }
      }
      const int b0 = (lg * 2 + 0) * DIP;
      const int b1 = (lg * 2 + 1) * DIP;
      for (int k = 0; k < DIP; k += 4) {
        float4 ev0 = *(const float4*)&sE[b0 + k];
        float4 ev1 = *(const float4*)&sE[b1 + k];
        float ea0[4] = {ev0.x, ev0.y, ev0.z, ev0.w};
        float ea1[4] = {ev1.x, ev1.y, ev1.z, ev1.w};
        #pragma unroll
        for (int kk = 0; kk < 4; kk++) {
          float4 wv = *(const float4*)&sW[(k + kk) * DOTP + cg * 4];
          acc[0][0] += ea0[kk] * wv.x; acc[0][1] += ea0[kk] * wv.y;
          acc[0][2] += ea0[kk] * wv.z; acc[0][3] += ea0[kk] * wv.w;
          acc[1][0] += ea1[kk] * wv.x; acc[1][1] += ea1[kk] * wv.y;
          acc[1][2] += ea1[kk] * wv.z; acc[1][3] += ea1[kk] * wv.w;
        }
      }
      #pragma unroll
      for (int li = 0; li < 2; li++) {
        const int le = lg * 2 + li;
        const int ge = e0 + le;
        float p = 0.f;
        if constexpr (DO % 4 == 0) {
          float fv[4];
          #pragma unroll
          for (int cc = 0; cc < 4; cc++) {
            float v = acc[li][cc];
            v = (v > 0.f) ? v : 0.01f * v;
            fv[cc] = v;
            if (SCORE) p += v * attn[ct + cg * 4 + cc];
          }
          if (le < ne) {
            float4 st = make_float4(fv[0], fv[1], fv[2], fv[3]);
            *(float4*)&fout[(size_t)ge * DO + ct + cg * 4] = st;
          }
        } else {
          #pragma unroll
          for (int cc = 0; cc < 4; cc++) {
            int col = ct + cg * 4 + cc;
            if (col < DO) {
              float v = acc[li][cc];
              v = (v > 0.f) ? v : 0.01f * v;
              if (le < ne) fout[(size_t)ge * DO + col] = v;
              if (SCORE) p += v * attn[col];
            }
          }
        }
        if constexpr (SCORE) {
          p += __shfl_xor(p, 4, 8);
          p += __shfl_xor(p, 2, 8);
          p += __shfl_xor(p, 1, 8);
          if (cg == 0) sScore[le] += p;   // single writer per le
        }
      }
    }
    if constexpr (SCORE) {
      __syncthreads();
      if (tid < ne) {
        float sc = sScore[tid];
        score[e0 + tid] = sc;
        atomicMax(&menc[sDst[tid]], enc_f(sc));
      }
    }
  }
}

__global__ __launch_bounds__(NTH) void softmax_ex_k(float* __restrict__ score,
    const int* __restrict__ dst, const unsigned* __restrict__ menc,
    float* __restrict__ ssum, int E)
{
  int i = blockIdx.x * NTH + threadIdx.x;
  if (i < E) {
    int d = dst[i];
    float ex = expf(score[i] - dec_f(menc[d]));
    score[i] = ex;
    atomicAdd(&ssum[d], ex);
  }
}

__global__ __launch_bounds__(NTH) void softmax_norm_k(float* __restrict__ score,
    const float* __restrict__ ssum, const int* __restrict__ dst, int E)
{
  int i = blockIdx.x * NTH + threadIdx.x;
  if (i < E) score[i] = score[i] / ssum[dst[i]];
}

template<int DO>
__global__ __launch_bounds__(NTH) void scatter_h_k(const float* __restrict__ a,
    const int* __restrict__ src, const int* __restrict__ dst,
    const float* __restrict__ h, float* __restrict__ hout, int E)
{
  int idx = blockIdx.x * NTH + threadIdx.x;
  if (idx < E * DO) {
    int e = idx / DO;
    int col = idx - e * DO;
    atomicAdd(&hout[(size_t)dst[e] * DO + col], h[(size_t)src[e] * DO + col] * a[e]);
  }
}

extern "C" void kernel_launch(void* const* d_in, const int* in_sizes, int n_in,
                              void* d_out, int out_size, void* d_ws, size_t ws_size,
                              hipStream_t stream)
{
  const float* x    = (const float*)d_in[0];
  const float* e    = (const float*)d_in[1];
  const int*   src  = (const int*)d_in[2];
  const int*   dst  = (const int*)d_in[3];
  const float* W_n1 = (const float*)d_in[4];   const float* b_n1  = (const float*)d_in[5];
  const float* W_ni1= (const float*)d_in[6];   const float* W_nj1 = (const float*)d_in[7];
  const float* W_f1 = (const float*)d_in[8];   const float* attn1 = (const float*)d_in[9];
  const float* bias1= (const float*)d_in[10];
  const float* W_n2 = (const float*)d_in[11];  const float* b_n2  = (const float*)d_in[12];
  const float* W_ni2= (const float*)d_in[13];  const float* W_nj2 = (const float*)d_in[14];
  const float* W_f2 = (const float*)d_in[15];  const float* attn2 = (const float*)d_in[16];
  const float* bias2= (const float*)d_in[17];
  const float* W_n3 = (const float*)d_in[18];  const float* b_n3  = (const float*)d_in[19];
  const float* W_ni3= (const float*)d_in[20];  const float* W_nj3 = (const float*)d_in[21];
  const float* W_f3 = (const float*)d_in[22];  const float* attn3 = (const float*)d_in[23];
  const float* bias3= (const float*)d_in[24];
  (void)W_n3; (void)b_n3;  // layer 3 aggregation output is unused (only f3 returned)

  const int N = in_sizes[0] / 128;
  const int E = in_sizes[2];

  float* ws = (float*)d_ws;
  size_t off = 0;
  float* fbuf1 = ws + off; off += (size_t)E * 128;   // f1 [E,128]
  float* fbuf2 = ws + off; off += (size_t)E * 30;    // f2 [E,30]
  float* xWni  = ws + off; off += (size_t)N * 128;
  float* xWnj  = ws + off; off += (size_t)N * 128;
  float* hbuf  = ws + off; off += (size_t)N * 128;
  float* nodeA = ws + off; off += (size_t)N * 128;   // h_out layer1
  float* nodeB = ws + off; off += (size_t)N * 30;    // h_out layer2
  float* scoreb= ws + off; off += (size_t)E;         // score -> ex -> a (in place)
  unsigned* menc = (unsigned*)(ws + off); off += (size_t)N;
  float* sbuf  = ws + off; off += (size_t)N;

  const int GP = 768;                 // persistent grid (256 CU x 3 blocks)
  const int gE = (E + NTH - 1) / NTH;

  // ---------------- layer 1: di=128, do=128 ----------------
  node_linear_k<128,128><<<GP,NTH,0,stream>>>(x, W_ni1, nullptr, xWni, N);
  node_linear_k<128,128><<<GP,NTH,0,stream>>>(x, W_nj1, nullptr, xWnj, N);
  node_linear_k<128,128><<<GP,NTH,0,stream>>>(x, W_n1,  b_n1,   hbuf, N);
  hipMemsetAsync(menc, 0, (size_t)N * 4, stream);   // enc(-inf) < 0 for all finite
  hipMemsetAsync(sbuf, 0, (size_t)N * 4, stream);
  hipMemsetAsync(nodeA, 0, (size_t)N * 128 * 4, stream);
  edge_f_k<128,128,true><<<GP,NTH,0,stream>>>(e, xWni, xWnj, W_f1, attn1, bias1,
                                              src, dst, fbuf1, scoreb, menc, E);
  softmax_ex_k<<<gE,NTH,0,stream>>>(scoreb, dst, menc, sbuf, E);
  softmax_norm_k<<<gE,NTH,0,stream>>>(scoreb, sbuf, dst, E);
  scatter_h_k<128><<<(int)(((size_t)E*128 + NTH-1)/NTH),NTH,0,stream>>>(scoreb, src, dst, hbuf, nodeA, E);

  // ---------------- layer 2: di=128, do=30 ----------------
  node_linear_k<128,30><<<GP,NTH,0,stream>>>(nodeA, W_ni2, nullptr, xWni, N);
  node_linear_k<128,30><<<GP,NTH,0,stream>>>(nodeA, W_nj2, nullptr, xWnj, N);
  node_linear_k<128,30><<<GP,NTH,0,stream>>>(nodeA, W_n2,  b_n2,   hbuf, N);
  hipMemsetAsync(menc, 0, (size_t)N * 4, stream);
  hipMemsetAsync(sbuf, 0, (size_t)N * 4, stream);
  hipMemsetAsync(nodeB, 0, (size_t)N * 30 * 4, stream);
  edge_f_k<128,30,true><<<GP,NTH,0,stream>>>(fbuf1, xWni, xWnj, W_f2, attn2, bias2,
                                             src, dst, fbuf2, scoreb, menc, E);
  softmax_ex_k<<<gE,NTH,0,stream>>>(scoreb, dst, menc, sbuf, E);
  softmax_norm_k<<<gE,NTH,0,stream>>>(scoreb, sbuf, dst, E);
  scatter_h_k<30><<<(int)(((size_t)E*30 + NTH-1)/NTH),NTH,0,stream>>>(scoreb, src, dst, hbuf, nodeB, E);

  // ---------------- layer 3: di=30, do=64 — only f3 needed ----------------
  node_linear_k<30,64><<<GP,NTH,0,stream>>>(nodeB, W_ni3, nullptr, xWni, N);
  node_linear_k<30,64><<<GP,NTH,0,stream>>>(nodeB, W_nj3, nullptr, xWnj, N);
  edge_f_k<30,64,false><<<GP,NTH,0,stream>>>(fbuf2, xWni, xWnj, W_f3, attn3, bias3,
                                             src, dst, (float*)d_out, nullptr, nullptr, E);
}

// Round 2
// 3031.612 us; speedup vs baseline: 1.1936x; 1.1936x over previous
//
#include <hip/hip_runtime.h>
#include <math.h>

#define NTH 256

__device__ __forceinline__ unsigned enc_f(float x){
  unsigned u = __float_as_uint(x);
  return (u & 0x80000000u) ? ~u : (u | 0x80000000u);
}
__device__ __forceinline__ float dec_f(unsigned v){
  unsigned u = (v & 0x80000000u) ? (v & 0x7FFFFFFFu) : ~v;
  return __uint_as_float(u);
}

// ---------------------------------------------------------------------------
// Node linear: out[N,DO] = x[N,DI] @ W[DI,DO] (+ bias)
// lane = row. acc[DO] in VGPRs. Per-lane float4 stream of own row (L1 reuses
// each 64B line over 4 k-steps). W[k*DO+j] is wave-uniform -> s_load (scalar
// cache), zero LDS/VALU cost for weights. No LDS anywhere.
// ---------------------------------------------------------------------------
template<int DI, int DIS, int DO, int DOS, int MINW>
__global__ __launch_bounds__(NTH, MINW) void node_linear_k(
    const float* __restrict__ x, const float* __restrict__ W,
    const float* __restrict__ bias, float* __restrict__ out, int N)
{
  const int lane = threadIdx.x & 63;
  const int wave = threadIdx.x >> 6;
  const int row = (blockIdx.x * (NTH >> 6) + wave) * 64 + lane;
  const bool valid = row < N;
  const int rr = valid ? row : (N - 1);
  const float* xr = x + (size_t)rr * DIS;

  float acc[DO];
  if (bias != nullptr) {
    #pragma unroll
    for (int j = 0; j < DO; j++) acc[j] = bias[j];
  } else {
    #pragma unroll
    for (int j = 0; j < DO; j++) acc[j] = 0.f;
  }

  constexpr int K4 = DI & ~3;
  for (int k = 0; k < K4; k += 4) {
    float4 ev = *(const float4*)(xr + k);
    float ea[4] = {ev.x, ev.y, ev.z, ev.w};
    #pragma unroll
    for (int kk = 0; kk < 4; kk++) {
      const float* wr = W + (size_t)(k + kk) * DO;
      #pragma unroll
      for (int j = 0; j < DO; j++)
        acc[j] = fmaf(ea[kk], wr[j], acc[j]);
    }
  }
  #pragma unroll
  for (int k = K4; k < DI; k++) {
    float ev = xr[k];
    const float* wr = W + (size_t)k * DO;
    #pragma unroll
    for (int j = 0; j < DO; j++)
      acc[j] = fmaf(ev, wr[j], acc[j]);
  }

  if (valid) {
    float* orow = out + (size_t)row * DOS;
    constexpr int J4 = DO & ~3;
    #pragma unroll
    for (int j = 0; j < J4; j += 4)
      *(float4*)(orow + j) = make_float4(acc[j], acc[j+1], acc[j+2], acc[j+3]);
    #pragma unroll
    for (int j = J4; j < DO; j++) orow[j] = acc[j];
  }
}

// ---------------------------------------------------------------------------
// Edge kernel: f = leaky_relu(xWni[src] + xWnj[dst] + e@Wf + bias)
// lane = edge. acc[DO] init from bias + gathered src/dst node rows, then
// e-row GEMM streamed per-lane with uniform-W s_loads. Score is a per-lane
// scalar reduction (lane owns the whole row) -> no shuffles.
// ---------------------------------------------------------------------------
template<int DI, int DIS, int DO, int DOS, bool SCORE, int MINW>
__global__ __launch_bounds__(NTH, MINW) void edge_f_k(
    const float* __restrict__ efeat, const float* __restrict__ xWni,
    const float* __restrict__ xWnj, const float* __restrict__ Wf,
    const float* __restrict__ attn, const float* __restrict__ bias,
    const int* __restrict__ src, const int* __restrict__ dst,
    float* __restrict__ fout, float* __restrict__ score,
    unsigned* __restrict__ menc, int E)
{
  const int lane = threadIdx.x & 63;
  const int wave = threadIdx.x >> 6;
  const int eidx = (blockIdx.x * (NTH >> 6) + wave) * 64 + lane;
  const bool valid = eidx < E;
  const int ee = valid ? eidx : (E - 1);

  const int sn = src[ee];
  const int dn = dst[ee];
  const float* ar = xWni + (size_t)sn * DOS;
  const float* br = xWnj + (size_t)dn * DOS;

  float acc[DO];
  constexpr int J4 = DO & ~3;
  #pragma unroll
  for (int j = 0; j < J4; j += 4) {
    float4 a4 = *(const float4*)(ar + j);
    float4 b4 = *(const float4*)(br + j);
    acc[j+0] = bias[j+0] + a4.x + b4.x;
    acc[j+1] = bias[j+1] + a4.y + b4.y;
    acc[j+2] = bias[j+2] + a4.z + b4.z;
    acc[j+3] = bias[j+3] + a4.w + b4.w;
  }
  #pragma unroll
  for (int j = J4; j < DO; j++)
    acc[j] = bias[j] + ar[j] + br[j];

  const float* er = efeat + (size_t)ee * DIS;
  constexpr int K4 = DI & ~3;
  for (int k = 0; k < K4; k += 4) {
    float4 ev = *(const float4*)(er + k);
    float ea[4] = {ev.x, ev.y, ev.z, ev.w};
    #pragma unroll
    for (int kk = 0; kk < 4; kk++) {
      const float* wr = Wf + (size_t)(k + kk) * DO;
      #pragma unroll
      for (int j = 0; j < DO; j++)
        acc[j] = fmaf(ea[kk], wr[j], acc[j]);
    }
  }
  #pragma unroll
  for (int k = K4; k < DI; k++) {
    float ev = er[k];
    const float* wr = Wf + (size_t)k * DO;
    #pragma unroll
    for (int j = 0; j < DO; j++)
      acc[j] = fmaf(ev, wr[j], acc[j]);
  }

  float sc = 0.f;
  #pragma unroll
  for (int j = 0; j < DO; j++) {
    float v = acc[j];
    v = (v > 0.f) ? v : 0.01f * v;
    acc[j] = v;
    if (SCORE) sc += v * attn[j];
  }

  if (valid) {
    float* orow = fout + (size_t)eidx * DOS;
    #pragma unroll
    for (int j = 0; j < J4; j += 4)
      *(float4*)(orow + j) = make_float4(acc[j], acc[j+1], acc[j+2], acc[j+3]);
    #pragma unroll
    for (int j = J4; j < DO; j++) orow[j] = acc[j];
    if constexpr (SCORE) {
      score[eidx] = sc;
      atomicMax(&menc[dn], enc_f(sc));
    }
  }
}

__global__ __launch_bounds__(NTH) void softmax_ex_k(float* __restrict__ score,
    const int* __restrict__ dst, const unsigned* __restrict__ menc,
    float* __restrict__ ssum, int E)
{
  int i = blockIdx.x * NTH + threadIdx.x;
  if (i < E) {
    int d = dst[i];
    float ex = expf(score[i] - dec_f(menc[d]));
    score[i] = ex;
    atomicAdd(&ssum[d], ex);
  }
}

__global__ __launch_bounds__(NTH) void softmax_norm_k(float* __restrict__ score,
    const float* __restrict__ ssum, const int* __restrict__ dst, int E)
{
  int i = blockIdx.x * NTH + threadIdx.x;
  if (i < E) score[i] = score[i] / ssum[dst[i]];
}

template<int DO, int HS, int OS>
__global__ __launch_bounds__(NTH) void scatter_h_k(const float* __restrict__ a,
    const int* __restrict__ src, const int* __restrict__ dst,
    const float* __restrict__ h, float* __restrict__ hout, int E)
{
  long long idx = (long long)blockIdx.x * NTH + threadIdx.x;
  if (idx < (long long)E * DO) {
    int e = (int)(idx / DO);
    int col = (int)(idx - (long long)e * DO);
    atomicAdd(&hout[(size_t)dst[e] * OS + col], h[(size_t)src[e] * HS + col] * a[e]);
  }
}

extern "C" void kernel_launch(void* const* d_in, const int* in_sizes, int n_in,
                              void* d_out, int out_size, void* d_ws, size_t ws_size,
                              hipStream_t stream)
{
  const float* x    = (const float*)d_in[0];
  const float* e    = (const float*)d_in[1];
  const int*   src  = (const int*)d_in[2];
  const int*   dst  = (const int*)d_in[3];
  const float* W_n1 = (const float*)d_in[4];   const float* b_n1  = (const float*)d_in[5];
  const float* W_ni1= (const float*)d_in[6];   const float* W_nj1 = (const float*)d_in[7];
  const float* W_f1 = (const float*)d_in[8];   const float* attn1 = (const float*)d_in[9];
  const float* bias1= (const float*)d_in[10];
  const float* W_n2 = (const float*)d_in[11];  const float* b_n2  = (const float*)d_in[12];
  const float* W_ni2= (const float*)d_in[13];  const float* W_nj2 = (const float*)d_in[14];
  const float* W_f2 = (const float*)d_in[15];  const float* attn2 = (const float*)d_in[16];
  const float* bias2= (const float*)d_in[17];
  const float* W_n3 = (const float*)d_in[18];  const float* b_n3  = (const float*)d_in[19];
  const float* W_ni3= (const float*)d_in[20];  const float* W_nj3 = (const float*)d_in[21];
  const float* W_f3 = (const float*)d_in[22];  const float* attn3 = (const float*)d_in[23];
  const float* bias3= (const float*)d_in[24];
  (void)W_n3; (void)b_n3;  // layer-3 node aggregation is dead (only f3 returned)

  const int N = in_sizes[0] / 128;
  const int E = in_sizes[2];

  float* ws = (float*)d_ws;
  size_t off = 0;
  float* fbuf1 = ws + off; off += (size_t)E * 128;   // f1 [E,128]
  float* fbuf2 = ws + off; off += (size_t)E * 32;    // f2 [E,30] padded to 32
  float* xWni  = ws + off; off += (size_t)N * 128;
  float* xWnj  = ws + off; off += (size_t)N * 128;
  float* hbuf  = ws + off; off += (size_t)N * 128;
  float* nodeA = ws + off; off += (size_t)N * 128;   // h_out layer1 [N,128]
  float* nodeB = ws + off; off += (size_t)N * 32;    // h_out layer2 [N,30] pad 32
  float* scoreb= ws + off; off += (size_t)E;         // score -> ex -> a (in place)
  unsigned* menc = (unsigned*)(ws + off); off += (size_t)N;
  float* sbuf  = ws + off; off += (size_t)N;

  const int gN = (N + NTH - 1) / NTH;   // 64 rows per wave, 4 waves/block
  const int gEe = (E + NTH - 1) / NTH;
  const int gE = gEe;

  // ---------------- layer 1: di=128 -> do=128 ----------------
  node_linear_k<128,128,128,128,2><<<gN,NTH,0,stream>>>(x, W_ni1, nullptr, xWni, N);
  node_linear_k<128,128,128,128,2><<<gN,NTH,0,stream>>>(x, W_nj1, nullptr, xWnj, N);
  node_linear_k<128,128,128,128,2><<<gN,NTH,0,stream>>>(x, W_n1,  b_n1,   hbuf, N);
  hipMemsetAsync(menc, 0, (size_t)N * 4, stream);   // enc(-inf)=0 lower bound
  hipMemsetAsync(sbuf, 0, (size_t)N * 4, stream);
  hipMemsetAsync(nodeA, 0, (size_t)N * 128 * 4, stream);
  edge_f_k<128,128,128,128,true,2><<<gE,NTH,0,stream>>>(e, xWni, xWnj, W_f1, attn1, bias1,
                                                        src, dst, fbuf1, scoreb, menc, E);
  softmax_ex_k<<<gEe,NTH,0,stream>>>(scoreb, dst, menc, sbuf, E);
  softmax_norm_k<<<gEe,NTH,0,stream>>>(scoreb, sbuf, dst, E);
  scatter_h_k<128,128,128><<<(int)(((long long)E*128 + NTH-1)/NTH),NTH,0,stream>>>(scoreb, src, dst, hbuf, nodeA, E);

  // ---------------- layer 2: di=128 -> do=30 (pad 32) ----------------
  node_linear_k<128,128,30,32,4><<<gN,NTH,0,stream>>>(nodeA, W_ni2, nullptr, xWni, N);
  node_linear_k<128,128,30,32,4><<<gN,NTH,0,stream>>>(nodeA, W_nj2, nullptr, xWnj, N);
  node_linear_k<128,128,30,32,4><<<gN,NTH,0,stream>>>(nodeA, W_n2,  b_n2,   hbuf, N);
  hipMemsetAsync(menc, 0, (size_t)N * 4, stream);
  hipMemsetAsync(sbuf, 0, (size_t)N * 4, stream);
  hipMemsetAsync(nodeB, 0, (size_t)N * 32 * 4, stream);
  edge_f_k<128,128,30,32,true,4><<<gE,NTH,0,stream>>>(fbuf1, xWni, xWnj, W_f2, attn2, bias2,
                                                      src, dst, fbuf2, scoreb, menc, E);
  softmax_ex_k<<<gEe,NTH,0,stream>>>(scoreb, dst, menc, sbuf, E);
  softmax_norm_k<<<gEe,NTH,0,stream>>>(scoreb, sbuf, dst, E);
  scatter_h_k<30,32,32><<<(int)(((long long)E*30 + NTH-1)/NTH),NTH,0,stream>>>(scoreb, src, dst, hbuf, nodeB, E);

  // ---------------- layer 3: di=30 (stride 32) -> do=64 — only f3 ----------------
  node_linear_k<30,32,64,64,3><<<gN,NTH,0,stream>>>(nodeB, W_ni3, nullptr, xWni, N);
  node_linear_k<30,32,64,64,3><<<gN,NTH,0,stream>>>(nodeB, W_nj3, nullptr, xWnj, N);
  edge_f_k<30,32,64,64,false,3><<<gE,NTH,0,stream>>>(fbuf2, xWni, xWnj, W_f3, attn3, bias3,
                                                     src, dst, (float*)d_out, nullptr, nullptr, E);
}